// Round 1
// 150.973 us; speedup vs baseline: 1.0175x; 1.0175x over previous
//
#include <hip/hip_runtime.h>

#define HIMG 256
#define WIMG 256
#define CCH  32
#define JBOX 64
#define BIMG 8
#define HGT  8
#define CPB  8     // channels per block
#define NCG  (CCH / CPB)
#define NXCD 8
#define LSEG 208   // staged logical cols from xs4: span <= 207 (proven from box bounds)
#define LPAD 216   // physical row: phi(c) = c + (c>>5); phi(207)=213, pad to 216

// R11: kill the LDS-pipe bottleneck (model: 60-70% of block budget was
// ds_read_b64 with up to 16-way bank conflicts at each_w≈4).
// - y-blend folded into staging (wy0/wy1 are block-uniform): LDS holds
//   blend[c] = row0[c]*wy1 + row1[c]*wy0 as FLOAT (half the read data).
// - Skewed layout phi(c) = c + (c>>5): odd per-32-col-group shift breaks
//   all stride-{1,2,3,4} bank patterns -> conflict-free reads.
// - Skew holes (slot 33g+32) are filled with a duplicate of col 32(g+1),
//   so taps (lx0, lx0+1) are ALWAYS physically adjacent -> the two scalar
//   reads merge into one ds_read2_b32 offset0:0 offset1:1 (8 reads/thread).
// Grid/swizzle identical to R9/R10 (32 blocks per box share one XCD).
__global__ __launch_bounds__(256, 6) void roi_kernel(
    const float* __restrict__ img,     // (B, C, HIMG, WIMG)
    const float* __restrict__ boxes,   // (B, J, 5)
    float* __restrict__ res,           // (B, J, C, HGT, max_w)
    float* __restrict__ mask,          // (B, J, max_w)
    int max_w)
{
    __shared__ float sblend[CPB][LPAD];   // 6,912 B

    const int d    = blockIdx.x;
    const int slot = d & (NXCD - 1);
    const int seq  = d >> 3;
    const int bj   = slot * ((BIMG * JBOX) / NXCD) + (seq >> 5);
    const int rem  = seq & 31;
    const int h    = rem >> 2;             // 0..7
    const int cg   = rem & 3;              // 0..3
    const int b    = bj >> 6;              // J = 64
    const int tid  = threadIdx.x;

    const float left = boxes[bj * 5 + 0];
    const float top  = boxes[bj * 5 + 1];
    const float bw   = boxes[bj * 5 + 2] - left;
    const float bh   = boxes[bj * 5 + 3] - top;

    // width = int32(bw/bh * 8) with f32 ops + truncation (matches numpy).
    const int   width  = (int)(bw / bh * 8.0f);
    const float each_w = bw / ((float)width - 1.0f);
    const float each_h = bh / 7.0f;

    // y taps (block-uniform). Separate mul/add roundings (match numpy).
    const float y  = __fadd_rn(__fmul_rn((float)h, each_h), top);
    const int   yf = (int)floorf(y);
    const int   y0 = min(max(yf,     0), HIMG - 1);
    const int   y1 = min(max(yf + 1, 0), HIMG - 1);
    const float wy1 = (float)y1 - y;
    const float wy0 = y - (float)y0;

    const int xs  = max((int)floorf(left), 0);   // <= 40
    const int xs4 = xs & ~3;                     // 16B-aligned window start

    // ---- staging: 2 iters x 256 threads cover 8 ch x 52 float4 slots.
    //      Pre-blend rows with (wy1, wy0); write skewed floats. ----
    {
        const float* base = img + ((size_t)b * CCH + cg * CPB) * (HIMG * WIMG);
        #pragma unroll
        for (int it = 0; it < 2; ++it) {
            const int item = it * 256 + tid;     // 0..511
            const int ch   = item >> 6;          // 0..7
            const int l    = item & 63;          // float4 slot
            if (l < 52) {                        // 52*4 = 208 cols
                const float* r0p = base + ((size_t)ch * HIMG + y0) * WIMG + xs4 + l * 4;
                const float* r1p = base + ((size_t)ch * HIMG + y1) * WIMG + xs4 + l * 4;
                const float4 q0 = *reinterpret_cast<const float4*>(r0p);  // 16B-aligned
                const float4 q1 = *reinterpret_cast<const float4*>(r1p);
                const float b0 = q0.x * wy1 + q1.x * wy0;
                const float b1 = q0.y * wy1 + q1.y * wy0;
                const float b2 = q0.z * wy1 + q1.z * wy0;
                const float b3 = q0.w * wy1 + q1.w * wy0;
                const int c = l * 4;
                const int p = c + (c >> 5);      // skew: +1 slot per 32-col group
                float* wp = &sblend[ch][p];
                wp[0] = b0;                      // pairs merge to ds_write2_b32
                wp[1] = b1;
                wp[2] = b2;
                wp[3] = b3;
                // fill the skew hole before this group: slot phi(c)-1 = 33g+32
                // duplicates col 32(g+1), making (lx0, lx0+1) always adjacent.
                if ((l & 7) == 0 && l != 0) {
                    wp[-1] = b0;
                }
            }
        }
    }

    __syncthreads();

    const int  i    = tid;
    const bool have = (i < max_w);
    const bool in_w = (i < width);

    if (h == 0 && cg == 0 && have) {
        mask[(size_t)bj * max_w + i] = in_w ? 1.0f : 0.0f;
    }

    float* resp = res + (((size_t)bj * CCH + cg * CPB) * HGT + h) * (size_t)max_w + i;
    const size_t c_stride = (size_t)HGT * max_w;

    if (!have) return;

    if (!in_w) {
        #pragma unroll
        for (int c = 0; c < CPB; ++c) {
            resp[(size_t)c * c_stride] = 0.0f;
        }
        return;
    }

    // x taps (per thread); separate roundings to match numpy floor exactly.
    // x <= right <= 240 < 255, x >= left >= 0  =>  x0 = floor(x), x1 = x0+1
    // always (no clamp binds), so one adjacent pair per channel suffices.
    const float x  = __fadd_rn(__fmul_rn((float)i, each_w), left);
    const int   xf = (int)floorf(x);
    const int   x0 = min(max(xf, 0), WIMG - 1);
    const float wx1 = (float)(x0 + 1) - x;
    const float wx0 = x - (float)x0;

    const int lx0 = min(max(x0 - xs4, 0), LSEG - 2);
    const int p0  = lx0 + (lx0 >> 5);            // skewed physical index

    const float* rp = &sblend[0][p0];
    #pragma unroll
    for (int c = 0; c < CPB; ++c) {
        const float v0 = rp[0];                  // ds_read2_b32 offset0:0
        const float v1 = rp[1];                  //               offset1:1
        resp[(size_t)c * c_stride] = v0 * wx1 + v1 * wx0;
        rp += LPAD;
    }
}

extern "C" void kernel_launch(void* const* d_in, const int* in_sizes, int n_in,
                              void* d_out, int out_size, void* d_ws, size_t ws_size,
                              hipStream_t stream) {
    const float* img   = (const float*)d_in[0];
    const float* boxes = (const float*)d_in[1];
    float* out = (float*)d_out;

    const int per_w = BIMG * JBOX * CCH * HGT + BIMG * JBOX;  // 131584
    const int max_w = out_size / per_w;

    float* res  = out;
    float* mask = out + (size_t)BIMG * JBOX * CCH * HGT * max_w;

    const int blocks = BIMG * JBOX * HGT * NCG;   // 16384
    roi_kernel<<<blocks, 256, 0, stream>>>(img, boxes, res, mask, max_w);
}